// Round 1
// baseline (13259.943 us; speedup 1.0000x reference)
//
#include <hip/hip_runtime.h>
#include <hip/hip_bf16.h>
#include <math.h>

// Problem dims
#define BB 32
#define TE 80
#define FEAT 4096
#define HH 256
#define W2V 256
#define TD 30
#define VV 32000
#define G4 1024   // 4*H

__device__ __forceinline__ float sigm(float x) { return 1.0f / (1.0f + expf(-x)); }

// ---------------------------------------------------------------------------
// init: zero states (h1,c1,h2,c2 contiguous), loss, precompute bias sums
__global__ __launch_bounds__(256) void init_kernel(
    const float* __restrict__ b_ih1, const float* __restrict__ b_hh1,
    const float* __restrict__ b_ih2, const float* __restrict__ b_hh2,
    float* __restrict__ states, float* __restrict__ bias1,
    float* __restrict__ bias2, float* __restrict__ loss) {
  int i = blockIdx.x * 256 + threadIdx.x;
  if (i < 32768) states[i] = 0.0f;
  if (i < 1024) {
    bias1[i] = b_ih1[i] + b_hh1[i];
    bias2[i] = b_ih2[i] + b_hh2[i];
  }
  if (i == 0) *loss = 0.0f;
}

// ---------------------------------------------------------------------------
// transpose w_out [V][H] -> w_outT [H][V]  (coalesced writes)
__global__ __launch_bounds__(256) void transpose_wout(
    const float* __restrict__ w_out, float* __restrict__ w_outT) {
  int n = blockIdx.x * 256 + threadIdx.x;  // 0..31999
  int k = blockIdx.y;                      // 0..255
  w_outT[k * VV + n] = w_out[n * HH + k];
}

// ---------------------------------------------------------------------------
// X1[r][n] = sum_k feat[r][k]*w_ih1[n][k] + bias1[n];  r in [0,2560), n in [0,1024)
#define BM 64
#define BN 64
#define BKK 16
__global__ __launch_bounds__(256) void gemm_x1_kernel(
    const float* __restrict__ A, const float* __restrict__ Bw,
    const float* __restrict__ bias, float* __restrict__ C) {
  __shared__ float As[BKK][BM + 1];
  __shared__ float Bs[BKK][BN + 1];
  int tid = threadIdx.x;
  int rBase = blockIdx.y * BM;
  int nBase = blockIdx.x * BN;
  int ty = tid >> 4, tx = tid & 15;
  float acc[4][4] = {};
  for (int k0 = 0; k0 < FEAT; k0 += BKK) {
    int e = tid * 4;
    int row = e >> 4;
    int kk = e & 15;
    const float4 a4 = *reinterpret_cast<const float4*>(&A[(size_t)(rBase + row) * FEAT + k0 + kk]);
    As[kk + 0][row] = a4.x; As[kk + 1][row] = a4.y; As[kk + 2][row] = a4.z; As[kk + 3][row] = a4.w;
    const float4 b4 = *reinterpret_cast<const float4*>(&Bw[(size_t)(nBase + row) * FEAT + k0 + kk]);
    Bs[kk + 0][row] = b4.x; Bs[kk + 1][row] = b4.y; Bs[kk + 2][row] = b4.z; Bs[kk + 3][row] = b4.w;
    __syncthreads();
#pragma unroll
    for (int q = 0; q < BKK; ++q) {
      float a[4], b[4];
#pragma unroll
      for (int i = 0; i < 4; i++) a[i] = As[q][ty * 4 + i];
#pragma unroll
      for (int j = 0; j < 4; j++) b[j] = Bs[q][tx * 4 + j];
#pragma unroll
      for (int i = 0; i < 4; i++)
#pragma unroll
        for (int j = 0; j < 4; j++) acc[i][j] += a[i] * b[j];
    }
    __syncthreads();
  }
#pragma unroll
  for (int i = 0; i < 4; i++) {
    int r = rBase + ty * 4 + i;
#pragma unroll
    for (int j = 0; j < 4; j++) {
      int n = nBase + tx * 4 + j;
      C[(size_t)r * G4 + n] = acc[i][j] + bias[n];
    }
  }
}

// ---------------------------------------------------------------------------
// XW2[t][b][gj] = caption[b][t][:] . w_ih2[gj][0:256] + bias2[gj]
__global__ __launch_bounds__(256) void xw2_kernel(
    const float* __restrict__ caption, const float* __restrict__ w_ih2,
    const float* __restrict__ bias2, float* __restrict__ XW2) {
  int t = blockIdx.x;  // 0..28
  int b = blockIdx.y;  // 0..31
  int j = threadIdx.x;
  __shared__ float ws[256];
  ws[j] = caption[((size_t)b * TD + t) * W2V + j];
  __syncthreads();
  float acc0 = 0, acc1 = 0, acc2 = 0, acc3 = 0;
#pragma unroll 4
  for (int k = 0; k < 256; k++) {
    float v = ws[k];
    acc0 += w_ih2[(j)*512 + k] * v;
    acc1 += w_ih2[(j + 256) * 512 + k] * v;
    acc2 += w_ih2[(j + 512) * 512 + k] * v;
    acc3 += w_ih2[(j + 768) * 512 + k] * v;
  }
  float* out = &XW2[((size_t)t * 32 + b) * G4];
  out[j]       = acc0 + bias2[j];
  out[j + 256] = acc1 + bias2[j + 256];
  out[j + 512] = acc2 + bias2[j + 512];
  out[j + 768] = acc3 + bias2[j + 768];
}

// ---------------------------------------------------------------------------
// targets[(s-1)*32+b] = argmax_v onehot[b][s][v],  s = blockIdx.x+1
__global__ __launch_bounds__(256) void argmax_kernel(
    const float* __restrict__ onehot, int* __restrict__ targets) {
  int s = blockIdx.x + 1;
  int b = blockIdx.y;
  int tid = threadIdx.x;
  const float* row = &onehot[((size_t)b * TD + s) * VV];
  float bv = -INFINITY;
  int bi = 0x7fffffff;
  for (int v = tid; v < VV; v += 256) {
    float x = row[v];
    if (x > bv || (x == bv && v < bi)) { bv = x; bi = v; }
  }
  __shared__ float sv[256];
  __shared__ int si[256];
  sv[tid] = bv; si[tid] = bi;
  __syncthreads();
  for (int off = 128; off; off >>= 1) {
    if (tid < off) {
      float ov = sv[tid + off]; int oi = si[tid + off];
      if (ov > sv[tid] || (ov == sv[tid] && oi < si[tid])) { sv[tid] = ov; si[tid] = oi; }
    }
    __syncthreads();
  }
  if (tid == 0) targets[blockIdx.x * 32 + b] = si[0];
}

// ---------------------------------------------------------------------------
// lstm1 step: gates = xadd[b*xstride + .] + h1 @ w_hh1^T ; update h1,c1 in place
__global__ __launch_bounds__(256) void lstm1_kernel(
    const float* __restrict__ xadd, int xstride,
    float* __restrict__ h1, float* __restrict__ c1,
    const float* __restrict__ w_hh1) {
  int b = blockIdx.x;
  int j = threadIdx.x;
  __shared__ float hs[256];
  hs[j] = h1[b * 256 + j];
  __syncthreads();
  float a0 = 0, a1 = 0, a2 = 0, a3 = 0;
#pragma unroll 8
  for (int k = 0; k < 256; k++) {
    float v = hs[k];
    a0 += w_hh1[(j)*256 + k] * v;
    a1 += w_hh1[(j + 256) * 256 + k] * v;
    a2 += w_hh1[(j + 512) * 256 + k] * v;
    a3 += w_hh1[(j + 768) * 256 + k] * v;
  }
  const float* xa = &xadd[(size_t)b * xstride];
  float gi = a0 + xa[j];
  float gf = a1 + xa[256 + j];
  float gg = a2 + xa[512 + j];
  float go = a3 + xa[768 + j];
  float c = sigm(gf) * c1[b * 256 + j] + sigm(gi) * tanhf(gg);
  float h = sigm(go) * tanhf(c);
  c1[b * 256 + j] = c;
  h1[b * 256 + j] = h;
}

// ---------------------------------------------------------------------------
// lstm2 step: gates = xadd + h1 @ w_ih2[:,256:]^T + h2in @ w_hh2^T
__global__ __launch_bounds__(256) void lstm2_kernel(
    const float* __restrict__ xadd, int xstride,
    const float* __restrict__ h1, const float* __restrict__ h2in,
    float* __restrict__ h2out, float* __restrict__ c2,
    const float* __restrict__ w_ih2, const float* __restrict__ w_hh2,
    float* __restrict__ enc_out, int has_enc) {
  int b = blockIdx.x;
  int j = threadIdx.x;
  __shared__ float h1s[256], h2s[256];
  h1s[j] = h1[b * 256 + j];
  h2s[j] = h2in[b * 256 + j];
  __syncthreads();
  float a0 = 0, a1 = 0, a2 = 0, a3 = 0;
#pragma unroll 4
  for (int k = 0; k < 256; k++) {
    float v1 = h1s[k], v2 = h2s[k];
    a0 += w_ih2[(j)*512 + 256 + k] * v1 + w_hh2[(j)*256 + k] * v2;
    a1 += w_ih2[(j + 256) * 512 + 256 + k] * v1 + w_hh2[(j + 256) * 256 + k] * v2;
    a2 += w_ih2[(j + 512) * 512 + 256 + k] * v1 + w_hh2[(j + 512) * 256 + k] * v2;
    a3 += w_ih2[(j + 768) * 512 + 256 + k] * v1 + w_hh2[(j + 768) * 256 + k] * v2;
  }
  const float* xa = &xadd[(size_t)b * xstride];
  float gi = a0 + xa[j];
  float gf = a1 + xa[256 + j];
  float gg = a2 + xa[512 + j];
  float go = a3 + xa[768 + j];
  float c = sigm(gf) * c2[b * 256 + j] + sigm(gi) * tanhf(gg);
  float h = sigm(go) * tanhf(c);
  c2[b * 256 + j] = c;
  h2out[b * 256 + j] = h;
  if (has_enc) enc_out[(size_t)b * TE * 256 + j] = h;  // enc_out pre-offset by t*256
}

// ---------------------------------------------------------------------------
// logits[b][n] = h2n[b][:] . w_outT[:][n] + b_out[n]
// 500 blocks x 64 n-cols; 4 k-slices of 64 per block; acc[32] batch per thread.
__global__ __launch_bounds__(256) void logits_kernel(
    const float* __restrict__ h2n, const float* __restrict__ w_outT,
    const float* __restrict__ b_out, float* __restrict__ logits) {
  __shared__ float smem[8192];
  int tid = threadIdx.x;
  int nBase = blockIdx.x * 64;
  for (int i = tid; i < 8192; i += 256) smem[i] = h2n[i];
  __syncthreads();
  int l = tid & 63;
  int n = nBase + l;
  int ks = tid >> 6;  // 0..3
  float acc[32];
#pragma unroll
  for (int b = 0; b < 32; b++) acc[b] = 0.0f;
  for (int kk = 0; kk < 64; ++kk) {
    int k = (ks << 6) + kk;
    float w = w_outT[(size_t)k * VV + n];
#pragma unroll
    for (int b = 0; b < 32; b++) acc[b] += w * smem[b * 256 + k];
  }
  __syncthreads();
  float* red = smem;  // reuse: [32 b][3 slices][64 l] = 6144 floats
  if (ks) {
#pragma unroll
    for (int b = 0; b < 32; b++) red[b * 192 + (ks - 1) * 64 + l] = acc[b];
  }
  __syncthreads();
  if (ks == 0) {
    float bo = b_out[n];
#pragma unroll
    for (int b = 0; b < 32; b++) {
      float s = acc[b] + red[b * 192 + l] + red[b * 192 + 64 + l] + red[b * 192 + 128 + l] + bo;
      logits[(size_t)b * VV + n] = s;
    }
  }
}

// ---------------------------------------------------------------------------
// loss += (logsumexp(logits[b]) - logits[b][tgt[b]]) / 1024
__global__ __launch_bounds__(256) void ce_kernel(
    const float* __restrict__ logits, const int* __restrict__ tgt,
    float* __restrict__ loss) {
  int b = blockIdx.x;
  int tid = threadIdx.x;
  const float* row = &logits[(size_t)b * VV];
  __shared__ float sm[256];
  float m = -INFINITY;
  for (int v = tid; v < VV; v += 256) m = fmaxf(m, row[v]);
  sm[tid] = m;
  __syncthreads();
  for (int off = 128; off; off >>= 1) {
    if (tid < off) sm[tid] = fmaxf(sm[tid], sm[tid + off]);
    __syncthreads();
  }
  m = sm[0];
  __syncthreads();
  float s = 0;
  for (int v = tid; v < VV; v += 256) s += expf(row[v] - m);
  sm[tid] = s;
  __syncthreads();
  for (int off = 128; off; off >>= 1) {
    if (tid < off) sm[tid] += sm[tid + off];
    __syncthreads();
  }
  if (tid == 0) {
    float lse = m + logf(sm[0]);
    float ce = lse - row[tgt[b]];
    atomicAdd(loss, ce * (1.0f / 1024.0f));
  }
}

// ---------------------------------------------------------------------------
// attention: scores over 80 enc states vs h2n; ctx -> h2out
__global__ __launch_bounds__(256) void attn_kernel(
    const float* __restrict__ enc, const float* __restrict__ h2n,
    float* __restrict__ h2out) {
  int b = blockIdx.x;
  int tid = threadIdx.x;
  __shared__ float q[256];
  __shared__ float sc[80];
  __shared__ float ms[2];
  q[tid] = h2n[b * 256 + tid];
  __syncthreads();
  if (tid < 80) {
    const float* e = &enc[((size_t)b * TE + tid) * 256];
    float a = 0;
#pragma unroll 8
    for (int k = 0; k < 256; k++) a += e[k] * q[k];
    sc[tid] = a;
  }
  __syncthreads();
  if (tid == 0) {
    float m = -INFINITY;
    for (int s2 = 0; s2 < 80; s2++) m = fmaxf(m, sc[s2]);
    float sum = 0;
    for (int s2 = 0; s2 < 80; s2++) sum += expf(sc[s2] - m);
    ms[0] = m;
    ms[1] = 1.0f / sum;
  }
  __syncthreads();
  if (tid < 80) sc[tid] = expf(sc[tid] - ms[0]) * ms[1];
  __syncthreads();
  float a = 0;
#pragma unroll 8
  for (int s2 = 0; s2 < 80; s2++) a += sc[s2] * enc[((size_t)b * TE + s2) * 256 + tid];
  h2out[b * 256 + tid] = a;
}

// ---------------------------------------------------------------------------
__global__ void finalize_kernel(const float* __restrict__ loss, float* __restrict__ out) {
  if (threadIdx.x == 0) out[0] = loss[0];
}

// ---------------------------------------------------------------------------
extern "C" void kernel_launch(void* const* d_in, const int* in_sizes, int n_in,
                              void* d_out, int out_size, void* d_ws, size_t ws_size,
                              hipStream_t stream) {
  (void)in_sizes; (void)n_in; (void)out_size; (void)ws_size;
  const float* feat    = (const float*)d_in[0];
  const float* caption = (const float*)d_in[1];
  const float* onehot  = (const float*)d_in[2];
  const float* w_ih1   = (const float*)d_in[4];
  const float* w_hh1   = (const float*)d_in[5];
  const float* b_ih1   = (const float*)d_in[6];
  const float* b_hh1   = (const float*)d_in[7];
  const float* w_ih2   = (const float*)d_in[8];
  const float* w_hh2   = (const float*)d_in[9];
  const float* b_ih2   = (const float*)d_in[10];
  const float* b_hh2   = (const float*)d_in[11];
  const float* w_out   = (const float*)d_in[12];
  const float* b_out   = (const float*)d_in[13];

  float* ws = (float*)d_ws;
  float* X1      = ws;                      // 2,621,440
  float* XW2     = X1 + 2621440;            // 950,272
  float* bias1   = XW2 + 950272;            // 1024
  float* bias2   = bias1 + 1024;            // 1024
  float* states  = bias2 + 1024;            // 32768 = h1,c1,h2,c2
  float* h1 = states;
  float* c1 = states + 8192;
  float* h2 = states + 16384;
  float* c2 = states + 24576;
  float* h2n     = states + 32768;          // 8192
  float* encb    = h2n + 8192;              // 655,360  [b][t][j]
  float* logits  = encb + 655360;           // 1,024,000
  float* w_outT  = logits + 1024000;        // 8,192,000
  float* lossacc = w_outT + 8192000;        // 1
  int*   targets = (int*)(lossacc + 1);     // 29*32

  init_kernel<<<128, 256, 0, stream>>>(b_ih1, b_hh1, b_ih2, b_hh2, states, bias1, bias2, lossacc);
  transpose_wout<<<dim3(125, 256), 256, 0, stream>>>(w_out, w_outT);
  gemm_x1_kernel<<<dim3(16, 40), 256, 0, stream>>>(feat, w_ih1, bias1, X1);
  xw2_kernel<<<dim3(29, 32), 256, 0, stream>>>(caption, w_ih2, bias2, XW2);
  argmax_kernel<<<dim3(29, 32), 256, 0, stream>>>(onehot, targets);

  // ----- encoder: 80 steps -----
  for (int t = 0; t < TE; ++t) {
    lstm1_kernel<<<32, 256, 0, stream>>>(X1 + (size_t)t * G4, TE * G4, h1, c1, w_hh1);
    lstm2_kernel<<<32, 256, 0, stream>>>(bias2, 0, h1, h2, h2, c2, w_ih2, w_hh2,
                                         encb + (size_t)t * 256, 1);
  }

  // ----- decoder: 29 steps -----
  for (int s = 0; s < TD - 1; ++s) {
    lstm1_kernel<<<32, 256, 0, stream>>>(bias1, 0, h1, c1, w_hh1);
    lstm2_kernel<<<32, 256, 0, stream>>>(XW2 + (size_t)s * 32 * G4, G4, h1, h2, h2n, c2,
                                         w_ih2, w_hh2, nullptr, 0);
    logits_kernel<<<500, 256, 0, stream>>>(h2n, w_outT, b_out, logits);
    ce_kernel<<<32, 256, 0, stream>>>(logits, targets + s * 32, lossacc);
    attn_kernel<<<32, 256, 0, stream>>>(encb, h2n, h2);
  }

  finalize_kernel<<<1, 64, 0, stream>>>(lossacc, (float*)d_out);
}

// Round 2
// 4442.228 us; speedup vs baseline: 2.9850x; 2.9850x over previous
//
#include <hip/hip_runtime.h>
#include <hip/hip_bf16.h>
#include <math.h>

// Problem dims
#define BB 32
#define TE 80
#define FEAT 4096
#define HH 256
#define W2V 256
#define TD 30
#define VV 32000
#define G4 1024   // 4*H

typedef unsigned short u16;
typedef unsigned int u32;
using f32x4 = __attribute__((ext_vector_type(4))) float;
using bf16x8 = __attribute__((ext_vector_type(8))) short;

__device__ __forceinline__ float sigm(float x) { return 1.0f / (1.0f + expf(-x)); }
__device__ __forceinline__ u16 f2bf(float f) {
  u32 u = __float_as_uint(f);
  u32 r = (u + 0x7FFFu + ((u >> 16) & 1u)) >> 16;
  return (u16)r;
}
__device__ __forceinline__ float bflo(u32 p) { return __uint_as_float(p << 16); }
__device__ __forceinline__ float bfhi(u32 p) { return __uint_as_float(p & 0xFFFF0000u); }

// ---------------------------------------------------------------------------
// init: zero states (h1a,h1b,h2a,h2b,c1,c2 = 6*8192), loss; bias sums
__global__ __launch_bounds__(256) void init_kernel(
    const float* __restrict__ b_ih1, const float* __restrict__ b_hh1,
    const float* __restrict__ b_ih2, const float* __restrict__ b_hh2,
    float* __restrict__ states, float* __restrict__ bias1,
    float* __restrict__ bias2, float* __restrict__ loss) {
  int i = blockIdx.x * 256 + threadIdx.x;
  if (i < 49152) states[i] = 0.0f;
  if (i < 1024) {
    bias1[i] = b_ih1[i] + b_hh1[i];
    bias2[i] = b_ih2[i] + b_hh2[i];
  }
  if (i == 0) *loss = 0.0f;
}

// ---------------------------------------------------------------------------
// f32 -> bf16 contiguous, n4 float4s
__global__ __launch_bounds__(256) void conv_bf16_kernel(
    const float* __restrict__ in, u16* __restrict__ out, int n4) {
  int i = blockIdx.x * 256 + threadIdx.x;
  if (i < n4) {
    float4 v = *(const float4*)&in[(size_t)i * 4];
    *(ushort4*)&out[(size_t)i * 4] =
        make_ushort4(f2bf(v.x), f2bf(v.y), f2bf(v.z), f2bf(v.w));
  }
}

// w_ih2[:, 256:512] -> bf16 [1024][256]
__global__ __launch_bounds__(256) void conv_ih2r_kernel(
    const float* __restrict__ in, u16* __restrict__ out) {
  int i = (blockIdx.x * 256 + threadIdx.x) * 4;
  int row = i >> 8, k = i & 255;
  float4 v = *(const float4*)&in[(size_t)row * 512 + 256 + k];
  *(ushort4*)&out[(size_t)row * 256 + k] =
      make_ushort4(f2bf(v.x), f2bf(v.y), f2bf(v.z), f2bf(v.w));
}

// ---------------------------------------------------------------------------
// tiled transpose+convert: w_out [V][H] f32 -> w_outTb [H][V] bf16
__global__ __launch_bounds__(256) void transpose_wout(
    const float* __restrict__ w_out, u16* __restrict__ wT) {
  __shared__ float tile[64][65];
  int n0 = blockIdx.x * 64, k0 = blockIdx.y * 64;
  int tid = threadIdx.x;
#pragma unroll
  for (int i = 0; i < 4; ++i) {
    int f = i * 256 + tid;  // 0..1023 float4 ids
    int r = f >> 4, c = (f & 15) << 2;
    float4 v = *(const float4*)&w_out[(size_t)(n0 + r) * HH + k0 + c];
    tile[r][c] = v.x; tile[r][c + 1] = v.y; tile[r][c + 2] = v.z; tile[r][c + 3] = v.w;
  }
  __syncthreads();
  int kk = tid >> 2, nn0 = (tid & 3) << 4;
  u32 pk[8];
#pragma unroll
  for (int i = 0; i < 8; ++i) {
    u16 lo = f2bf(tile[nn0 + 2 * i][kk]);
    u16 hi = f2bf(tile[nn0 + 2 * i + 1][kk]);
    pk[i] = (u32)lo | ((u32)hi << 16);
  }
  u32* dst = (u32*)&wT[(size_t)(k0 + kk) * VV + n0 + nn0];
#pragma unroll
  for (int i = 0; i < 8; ++i) dst[i] = pk[i];
}

// ---------------------------------------------------------------------------
// MFMA GEMM: X1[r][n] = feat[r][:] . w_ih1b[n][:] + bias1[n]
// r in [0,2560), n in [0,1024), K=4096. A f32 (converted on the fly), B bf16.
#define GBM 128
#define GBN 128
#define GBK 64
#define LDST 72  // padded LDS row stride (ushorts); 144B = 16B-aligned, 2-way banks

__global__ __launch_bounds__(256) void gemm_x1_kernel(
    const float* __restrict__ A, const u16* __restrict__ Bw,
    const float* __restrict__ bias, float* __restrict__ C) {
  __shared__ __align__(16) u16 As[GBM * LDST];
  __shared__ __align__(16) u16 Bs[GBN * LDST];
  int tid = threadIdx.x;
  int rBase = blockIdx.y * GBM;
  int nBase = blockIdx.x * GBN;
  int lane = tid & 63, w = tid >> 6;
  int wrow = (w >> 1) * 64, wcol = (w & 1) * 64;
  int lrow = lane & 15, lk = (lane >> 4) * 8;

  f32x4 acc[4][4];
#pragma unroll
  for (int m = 0; m < 4; ++m)
#pragma unroll
    for (int n = 0; n < 4; ++n) acc[m][n] = (f32x4){0.f, 0.f, 0.f, 0.f};

  for (int k0 = 0; k0 < FEAT; k0 += GBK) {
    // stage A: 128x64 f32 -> bf16 LDS
#pragma unroll
    for (int i = 0; i < 8; ++i) {
      int f = i * 256 + tid;  // float4 id 0..2047
      int r = f >> 4, c = (f & 15) << 2;
      float4 v = *(const float4*)&A[(size_t)(rBase + r) * FEAT + k0 + c];
      *(ushort4*)&As[r * LDST + c] =
          make_ushort4(f2bf(v.x), f2bf(v.y), f2bf(v.z), f2bf(v.w));
    }
    // stage B: 128x64 bf16 LDS
#pragma unroll
    for (int i = 0; i < 4; ++i) {
      int f = i * 256 + tid;  // ushort8 id 0..1023
      int r = f >> 3, c = (f & 7) << 3;
      uint4 v = *(const uint4*)&Bw[(size_t)(nBase + r) * FEAT + k0 + c];
      *(uint4*)&Bs[r * LDST + c] = v;
    }
    __syncthreads();
    bf16x8 af[4][2], bfr[4][2];
#pragma unroll
    for (int m = 0; m < 4; ++m)
#pragma unroll
      for (int s2 = 0; s2 < 2; ++s2)
        af[m][s2] = *(const bf16x8*)&As[(wrow + m * 16 + lrow) * LDST + s2 * 32 + lk];
#pragma unroll
    for (int n = 0; n < 4; ++n)
#pragma unroll
      for (int s2 = 0; s2 < 2; ++s2)
        bfr[n][s2] = *(const bf16x8*)&Bs[(wcol + n * 16 + lrow) * LDST + s2 * 32 + lk];
#pragma unroll
    for (int s2 = 0; s2 < 2; ++s2)
#pragma unroll
      for (int m = 0; m < 4; ++m)
#pragma unroll
        for (int n = 0; n < 4; ++n)
          acc[m][n] = __builtin_amdgcn_mfma_f32_16x16x32_bf16(
              af[m][s2], bfr[n][s2], acc[m][n], 0, 0, 0);
    __syncthreads();
  }
  // epilogue: C/D layout col=lane&15, row=(lane>>4)*4+q
  int orow = (lane >> 4) * 4;
  int ocol = lane & 15;
#pragma unroll
  for (int m = 0; m < 4; ++m)
#pragma unroll
    for (int n = 0; n < 4; ++n) {
      int cidx = nBase + wcol + n * 16 + ocol;
      float bv = bias[cidx];
#pragma unroll
      for (int q = 0; q < 4; ++q) {
        int r = rBase + wrow + m * 16 + orow + q;
        C[(size_t)r * G4 + cidx] = acc[m][n][q] + bv;
      }
    }
}

// ---------------------------------------------------------------------------
// XW2[t][b][gj] = caption[b][t][:] . w_ih2[gj][0:256] + bias2[gj]  (f32, one-time)
__global__ __launch_bounds__(256) void xw2_kernel(
    const float* __restrict__ caption, const float* __restrict__ w_ih2,
    const float* __restrict__ bias2, float* __restrict__ XW2) {
  int t = blockIdx.x;
  int b = blockIdx.y;
  int j = threadIdx.x;
  __shared__ float wsm[256];
  wsm[j] = caption[((size_t)b * TD + t) * W2V + j];
  __syncthreads();
  float acc0 = 0, acc1 = 0, acc2 = 0, acc3 = 0;
#pragma unroll 4
  for (int k = 0; k < 256; k++) {
    float v = wsm[k];
    acc0 += w_ih2[(j)*512 + k] * v;
    acc1 += w_ih2[(j + 256) * 512 + k] * v;
    acc2 += w_ih2[(j + 512) * 512 + k] * v;
    acc3 += w_ih2[(j + 768) * 512 + k] * v;
  }
  float* out = &XW2[((size_t)t * 32 + b) * G4];
  out[j] = acc0 + bias2[j];
  out[j + 256] = acc1 + bias2[j + 256];
  out[j + 512] = acc2 + bias2[j + 512];
  out[j + 768] = acc3 + bias2[j + 768];
}

// ---------------------------------------------------------------------------
__global__ __launch_bounds__(256) void argmax_kernel(
    const float* __restrict__ onehot, int* __restrict__ targets) {
  int s = blockIdx.x + 1;
  int b = blockIdx.y;
  int tid = threadIdx.x;
  const float* row = &onehot[((size_t)b * TD + s) * VV];
  float bv = -INFINITY;
  int bi = 0x7fffffff;
  for (int v = tid; v < VV; v += 256) {
    float x = row[v];
    if (x > bv || (x == bv && v < bi)) { bv = x; bi = v; }
  }
  __shared__ float sv[256];
  __shared__ int si[256];
  sv[tid] = bv; si[tid] = bi;
  __syncthreads();
  for (int off = 128; off; off >>= 1) {
    if (tid < off) {
      float ov = sv[tid + off]; int oi = si[tid + off];
      if (ov > sv[tid] || (ov == sv[tid] && oi < si[tid])) { sv[tid] = ov; si[tid] = oi; }
    }
    __syncthreads();
  }
  if (tid == 0) targets[blockIdx.x * 32 + b] = si[0];
}

// ---------------------------------------------------------------------------
// lstm1 step: grid (4 jq, 32 b). gates = xadd + h1in @ w_hh1b^T; h1out, c1 update.
__global__ __launch_bounds__(256) void lstm1_kernel(
    const float* __restrict__ xadd, int xstride,
    const float* __restrict__ h1in, float* __restrict__ h1out,
    float* __restrict__ c1, const u16* __restrict__ w) {
  int b = blockIdx.y, jq = blockIdx.x;
  int tid = threadIdx.x;
  int g = tid >> 6, jj = tid & 63;
  int j = (jq << 6) + jj;
  int row = (g << 8) + j;
  __shared__ __align__(16) float hs[256];
  __shared__ float gsm[3][64];
  hs[tid] = h1in[(b << 8) + tid];
  __syncthreads();
  const uint4* wv = (const uint4*)(w + (size_t)row * 256);
  const float4* hv = (const float4*)hs;
  float acc = 0.f;
#pragma unroll 4
  for (int q = 0; q < 32; ++q) {
    uint4 a = wv[q];
    float4 x0 = hv[2 * q], x1 = hv[2 * q + 1];
    acc += bflo(a.x) * x0.x + bfhi(a.x) * x0.y + bflo(a.y) * x0.z + bfhi(a.y) * x0.w +
           bflo(a.z) * x1.x + bfhi(a.z) * x1.y + bflo(a.w) * x1.z + bfhi(a.w) * x1.w;
  }
  if (g) gsm[g - 1][jj] = acc;
  __syncthreads();
  if (g == 0) {
    const float* xa = xadd + (size_t)b * xstride;
    float gi = acc + xa[j];
    float gf = gsm[0][jj] + xa[256 + j];
    float gg = gsm[1][jj] + xa[512 + j];
    float go = gsm[2][jj] + xa[768 + j];
    int idx = (b << 8) + j;
    float c = sigm(gf) * c1[idx] + sigm(gi) * tanhf(gg);
    float h = sigm(go) * tanhf(c);
    c1[idx] = c;
    h1out[idx] = h;
  }
}

// ---------------------------------------------------------------------------
// lstm2 step: grid (4 jq, 32 b). gates = xadd + h1 @ wih2r^T + h2in @ whh2^T
__global__ __launch_bounds__(256) void lstm2_kernel(
    const float* __restrict__ xadd, int xstride,
    const float* __restrict__ h1, const float* __restrict__ h2in,
    float* __restrict__ h2out, float* __restrict__ c2,
    const u16* __restrict__ wih2r, const u16* __restrict__ whh2,
    float* __restrict__ enc_out, int has_enc) {
  int b = blockIdx.y, jq = blockIdx.x;
  int tid = threadIdx.x;
  int g = tid >> 6, jj = tid & 63;
  int j = (jq << 6) + jj;
  int row = (g << 8) + j;
  __shared__ __align__(16) float h1s[256], h2s[256];
  __shared__ float gsm[3][64];
  h1s[tid] = h1[(b << 8) + tid];
  h2s[tid] = h2in[(b << 8) + tid];
  __syncthreads();
  const uint4* w1 = (const uint4*)(wih2r + (size_t)row * 256);
  const uint4* w2 = (const uint4*)(whh2 + (size_t)row * 256);
  const float4* hv1 = (const float4*)h1s;
  const float4* hv2 = (const float4*)h2s;
  float acc = 0.f;
#pragma unroll 4
  for (int q = 0; q < 32; ++q) {
    uint4 a = w1[q];
    float4 x0 = hv1[2 * q], x1 = hv1[2 * q + 1];
    acc += bflo(a.x) * x0.x + bfhi(a.x) * x0.y + bflo(a.y) * x0.z + bfhi(a.y) * x0.w +
           bflo(a.z) * x1.x + bfhi(a.z) * x1.y + bflo(a.w) * x1.z + bfhi(a.w) * x1.w;
  }
#pragma unroll 4
  for (int q = 0; q < 32; ++q) {
    uint4 a = w2[q];
    float4 x0 = hv2[2 * q], x1 = hv2[2 * q + 1];
    acc += bflo(a.x) * x0.x + bfhi(a.x) * x0.y + bflo(a.y) * x0.z + bfhi(a.y) * x0.w +
           bflo(a.z) * x1.x + bfhi(a.z) * x1.y + bflo(a.w) * x1.z + bfhi(a.w) * x1.w;
  }
  if (g) gsm[g - 1][jj] = acc;
  __syncthreads();
  if (g == 0) {
    const float* xa = xadd + (size_t)b * xstride;
    float gi = acc + xa[j];
    float gf = gsm[0][jj] + xa[256 + j];
    float gg = gsm[1][jj] + xa[512 + j];
    float go = gsm[2][jj] + xa[768 + j];
    int idx = (b << 8) + j;
    float c = sigm(gf) * c2[idx] + sigm(gi) * tanhf(gg);
    float h = sigm(go) * tanhf(c);
    c2[idx] = c;
    h2out[idx] = h;
    if (has_enc) enc_out[(size_t)b * TE * 256 + j] = h;
  }
}

// ---------------------------------------------------------------------------
// logits[b][n] = h2n[b][:] . w_outTb[:][n] + b_out[n]   (bf16 weights)
__global__ __launch_bounds__(256) void logits_kernel(
    const float* __restrict__ h2n, const u16* __restrict__ wT,
    const float* __restrict__ b_out, float* __restrict__ logits) {
  __shared__ float smem[8192];
  int tid = threadIdx.x;
  int nBase = blockIdx.x * 64;
  for (int i = tid; i < 8192; i += 256) smem[i] = h2n[i];
  __syncthreads();
  int l = tid & 63;
  int n = nBase + l;
  int ks = tid >> 6;
  float acc[32];
#pragma unroll
  for (int b = 0; b < 32; b++) acc[b] = 0.0f;
  for (int kk = 0; kk < 64; ++kk) {
    int k = (ks << 6) + kk;
    float w = __uint_as_float(((u32)wT[(size_t)k * VV + n]) << 16);
#pragma unroll
    for (int b = 0; b < 32; b++) acc[b] += w * smem[b * 256 + k];
  }
  __syncthreads();
  float* red = smem;
  if (ks) {
#pragma unroll
    for (int b = 0; b < 32; b++) red[b * 192 + (ks - 1) * 64 + l] = acc[b];
  }
  __syncthreads();
  if (ks == 0) {
    float bo = b_out[n];
#pragma unroll
    for (int b = 0; b < 32; b++) {
      float s = acc[b] + red[b * 192 + l] + red[b * 192 + 64 + l] + red[b * 192 + 128 + l] + bo;
      logits[(size_t)b * VV + n] = s;
    }
  }
}

// ---------------------------------------------------------------------------
__global__ __launch_bounds__(256) void ce_kernel(
    const float* __restrict__ logits, const int* __restrict__ tgt,
    float* __restrict__ loss) {
  int b = blockIdx.x;
  int tid = threadIdx.x;
  const float* row = &logits[(size_t)b * VV];
  __shared__ float sm[256];
  float m = -INFINITY;
  for (int v = tid; v < VV; v += 256) m = fmaxf(m, row[v]);
  sm[tid] = m;
  __syncthreads();
  for (int off = 128; off; off >>= 1) {
    if (tid < off) sm[tid] = fmaxf(sm[tid], sm[tid + off]);
    __syncthreads();
  }
  m = sm[0];
  __syncthreads();
  float s = 0;
  for (int v = tid; v < VV; v += 256) s += expf(row[v] - m);
  sm[tid] = s;
  __syncthreads();
  for (int off = 128; off; off >>= 1) {
    if (tid < off) sm[tid] += sm[tid + off];
    __syncthreads();
  }
  if (tid == 0) {
    float lse = m + logf(sm[0]);
    float ce = lse - row[tgt[b]];
    atomicAdd(loss, ce * (1.0f / 1024.0f));
  }
}

// ---------------------------------------------------------------------------
__global__ __launch_bounds__(256) void attn_kernel(
    const float* __restrict__ enc, const float* __restrict__ h2n,
    float* __restrict__ h2out) {
  int b = blockIdx.x;
  int tid = threadIdx.x;
  __shared__ float q[256];
  __shared__ float sc[80];
  __shared__ float ms[2];
  q[tid] = h2n[b * 256 + tid];
  __syncthreads();
  if (tid < 80) {
    const float* e = &enc[((size_t)b * TE + tid) * 256];
    float a = 0;
#pragma unroll 8
    for (int k = 0; k < 256; k++) a += e[k] * q[k];
    sc[tid] = a;
  }
  __syncthreads();
  if (tid == 0) {
    float m = -INFINITY;
    for (int s2 = 0; s2 < 80; s2++) m = fmaxf(m, sc[s2]);
    float sum = 0;
    for (int s2 = 0; s2 < 80; s2++) sum += expf(sc[s2] - m);
    ms[0] = m;
    ms[1] = 1.0f / sum;
  }
  __syncthreads();
  if (tid < 80) sc[tid] = expf(sc[tid] - ms[0]) * ms[1];
  __syncthreads();
  float a = 0;
#pragma unroll 8
  for (int s2 = 0; s2 < 80; s2++) a += sc[s2] * enc[((size_t)b * TE + s2) * 256 + tid];
  h2out[b * 256 + tid] = a;
}

// ---------------------------------------------------------------------------
__global__ void finalize_kernel(const float* __restrict__ loss, float* __restrict__ out) {
  if (threadIdx.x == 0) out[0] = loss[0];
}

// ---------------------------------------------------------------------------
extern "C" void kernel_launch(void* const* d_in, const int* in_sizes, int n_in,
                              void* d_out, int out_size, void* d_ws, size_t ws_size,
                              hipStream_t stream) {
  (void)in_sizes; (void)n_in; (void)out_size; (void)ws_size;
  const float* feat    = (const float*)d_in[0];
  const float* caption = (const float*)d_in[1];
  const float* onehot  = (const float*)d_in[2];
  const float* w_ih1   = (const float*)d_in[4];
  const float* w_hh1   = (const float*)d_in[5];
  const float* b_ih1   = (const float*)d_in[6];
  const float* b_hh1   = (const float*)d_in[7];
  const float* w_ih2   = (const float*)d_in[8];
  const float* w_hh2   = (const float*)d_in[9];
  const float* b_ih2   = (const float*)d_in[10];
  const float* b_hh2   = (const float*)d_in[11];
  const float* w_out   = (const float*)d_in[12];
  const float* b_out   = (const float*)d_in[13];

  char* p = (char*)d_ws;
  auto alloc = [&](size_t bytes) {
    char* r = p;
    p += (bytes + 255) & ~(size_t)255;
    return r;
  };
  float* X1      = (float*)alloc(2560ull * 1024 * 4);     // 10.5 MB
  float* XW2     = (float*)alloc(29ull * 32 * 1024 * 4);  // 3.8 MB
  float* bias1   = (float*)alloc(1024 * 4);
  float* bias2   = (float*)alloc(1024 * 4);
  float* st      = (float*)alloc(6ull * 8192 * 4);        // h1a,h1b,h2a,h2b,c1,c2
  float* h2n     = (float*)alloc(8192 * 4);
  float* encb    = (float*)alloc(32ull * 80 * 256 * 4);   // 2.6 MB [b][t][j]
  float* logits  = (float*)alloc(32ull * VV * 4);         // 4.1 MB
  float* lossacc = (float*)alloc(256);
  int*   targets = (int*)alloc(29 * 32 * 4);
  u16*   w_ih1b  = (u16*)alloc(1024ull * 4096 * 2);       // 8.4 MB
  u16*   w_hh1b  = (u16*)alloc(1024ull * 256 * 2);
  u16*   w_ih2rb = (u16*)alloc(1024ull * 256 * 2);
  u16*   w_hh2b  = (u16*)alloc(1024ull * 256 * 2);
  u16*   w_outTb = (u16*)alloc(256ull * VV * 2);          // 16.4 MB

  float* h1a = st, *h1b = st + 8192, *h2a = st + 16384, *h2b = st + 24576;
  float* c1 = st + 32768, *c2 = st + 40960;

  init_kernel<<<192, 256, 0, stream>>>(b_ih1, b_hh1, b_ih2, b_hh2, st, bias1, bias2, lossacc);
  conv_bf16_kernel<<<4096, 256, 0, stream>>>(w_ih1, w_ih1b, 1048576);
  conv_bf16_kernel<<<256, 256, 0, stream>>>(w_hh1, w_hh1b, 65536);
  conv_bf16_kernel<<<256, 256, 0, stream>>>(w_hh2, w_hh2b, 65536);
  conv_ih2r_kernel<<<256, 256, 0, stream>>>(w_ih2, w_ih2rb);
  transpose_wout<<<dim3(500, 4), 256, 0, stream>>>(w_out, w_outTb);
  gemm_x1_kernel<<<dim3(8, 20), 256, 0, stream>>>(feat, w_ih1b, bias1, X1);
  xw2_kernel<<<dim3(29, 32), 256, 0, stream>>>(caption, w_ih2, bias2, XW2);
  argmax_kernel<<<dim3(29, 32), 256, 0, stream>>>(onehot, targets);

  float* h1cur = h1a; float* h1alt = h1b;
  float* h2cur = h2a; float* h2alt = h2b;

  // ----- encoder: 80 steps -----
  for (int t = 0; t < TE; ++t) {
    lstm1_kernel<<<dim3(4, 32), 256, 0, stream>>>(X1 + (size_t)t * G4, TE * G4,
                                                  h1cur, h1alt, c1, w_hh1b);
    { float* tmp = h1cur; h1cur = h1alt; h1alt = tmp; }
    lstm2_kernel<<<dim3(4, 32), 256, 0, stream>>>(bias2, 0, h1cur, h2cur, h2alt, c2,
                                                  w_ih2rb, w_hh2b,
                                                  encb + (size_t)t * 256, 1);
    { float* tmp = h2cur; h2cur = h2alt; h2alt = tmp; }
  }

  // ----- decoder: 29 steps -----
  for (int s = 0; s < TD - 1; ++s) {
    lstm1_kernel<<<dim3(4, 32), 256, 0, stream>>>(bias1, 0, h1cur, h1alt, c1, w_hh1b);
    { float* tmp = h1cur; h1cur = h1alt; h1alt = tmp; }
    lstm2_kernel<<<dim3(4, 32), 256, 0, stream>>>(XW2 + (size_t)s * 32 * G4, G4,
                                                  h1cur, h2cur, h2n, c2,
                                                  w_ih2rb, w_hh2b, nullptr, 0);
    logits_kernel<<<500, 256, 0, stream>>>(h2n, w_outTb, b_out, logits);
    ce_kernel<<<32, 256, 0, stream>>>(logits, targets + s * 32, lossacc);
    attn_kernel<<<32, 256, 0, stream>>>(encb, h2n, h2cur);  // ctx -> h2cur for next step
  }

  finalize_kernel<<<1, 64, 0, stream>>>(lossacc, (float*)d_out);
}